// Round 4
// baseline (256.939 us; speedup 1.0000x reference)
//
#include <hip/hip_runtime.h>
#include <hip/hip_bf16.h>

// HMLSTMCell2: B=65536, H=128, s = [hb*zb | h | ht*z](65536x384) @ Wc(384x513) + b.
// Cols 0..511 via bf16 MFMA 16x16x32; col 512 (sz -> z_new hard threshold) in fp64
// from the fp32 A tile in LDS. R3->R4: (a) prep_weights rewritten coalesced
// (was ~130us of strided gathers); (b) main K-loop restructured as async pipeline:
// W and A both staged 1 chunk ahead via global_load_lds into double buffers,
// raw s_waitcnt vmcnt(6) + s_barrier so prefetch stays in flight across the
// barrier (no vmcnt(0) drain); bf16 conversion + z-scaling done in compute phase.

#define MT   128         // rows per block
#define BK   32          // K chunk
#define NKC  12          // 384 / 32
#define NT   512         // threads per block
#define WCH  (512*BK)    // bf16 elements per W chunk (16384)
#define ACH  (MT*BK)     // fp32 elements per A chunk (4096)
#define COFF 8388608     // c_new offset in d_out (65536*128)
#define ZOFF 16777216    // z_new offset (2*65536*128)

using short8 = __attribute__((ext_vector_type(8))) short;  // 8 bf16 (4 VGPR)
using f32x4  = __attribute__((ext_vector_type(4))) float;  // MFMA acc frag

__device__ __forceinline__ unsigned short f2bf(float f) {
  union { float f; unsigned u; } v; v.f = f;
  unsigned r = (v.u + 0x7FFFu + ((v.u >> 16) & 1u)) >> 16;  // RNE
  return (unsigned short)r;
}

// pack two fp32 -> bf16x2 (round-half-up + byte-perm): 2 adds + 1 v_perm
__device__ __forceinline__ unsigned pk_bf2(float x, float y) {
  union { float f; unsigned u; } a, b; a.f = x; b.f = y;
  return __builtin_amdgcn_perm(b.u + 0x8000u, a.u + 0x8000u, 0x07060302u);
}

__device__ __forceinline__ void async_copy16(const void* g, void* l) {
  __builtin_amdgcn_global_load_lds(
      (const __attribute__((address_space(1))) unsigned int*)g,
      (__attribute__((address_space(3))) unsigned int*)l, 16, 0, 0);
}

__device__ __forceinline__ float sigm(float x)     { return 1.f / (1.f + __expf(-x)); }
__device__ __forceinline__ float tanh_fast(float x){ return 1.f - 2.f / (1.f + __expf(2.f * x)); }

// Wt layout (bf16): element ((c*512+n)*4 + (u ^ ((n>>1)&3)))*8 + j = Wc[c*32+u*8+j][n].
// WL (fp32, at Wt + NKC*WCH): WL[k] = Wc[k][512].
// Coalesced: block (c,g) loads rows k=c*32..+32, cols g*128..+128 row-wise, LDS
// transpose, writes 16B units contiguously.
__global__ __launch_bounds__(256)
void prep_weights(const float* __restrict__ W, const float* __restrict__ R,
                  const float* __restrict__ U, unsigned short* __restrict__ Wt,
                  float* __restrict__ WL) {
  __shared__ unsigned short T[32][136];   // bf16 tile, padded stride
  const int c = blockIdx.x >> 2, g = blockIdx.x & 3, tid = threadIdx.x;
  const int n0 = g * 128, k0 = c * 32;
  #pragma unroll 4
  for (int it = 0; it < 16; ++it) {
    int r = it * 2 + (tid >> 7);
    int k = k0 + r;
    const float* row = (k < 128) ? W + (size_t)k * 513
                     : (k < 256) ? R + (size_t)(k - 128) * 513
                                 : U + (size_t)(k - 256) * 513;
    T[r][tid & 127] = f2bf(row[n0 + (tid & 127)]);
  }
  if (g == 0 && tid < 32) {
    int k = k0 + tid;
    const float* row = (k < 128) ? W + (size_t)k * 513
                     : (k < 256) ? R + (size_t)(k - 128) * 513
                                 : U + (size_t)(k - 256) * 513;
    WL[k] = row[512];
  }
  __syncthreads();
  for (int t = tid; t < 512; t += 256) {
    int nl = t >> 2, u = t & 3;
    int n  = n0 + nl;
    int kl = (u ^ ((n >> 1) & 3)) * 8;
    unsigned short vs[8];
    #pragma unroll
    for (int j = 0; j < 8; ++j) vs[j] = T[kl + j][nl];
    uint4 o;
    o.x = (unsigned)vs[0] | ((unsigned)vs[1] << 16);
    o.y = (unsigned)vs[2] | ((unsigned)vs[3] << 16);
    o.z = (unsigned)vs[4] | ((unsigned)vs[5] << 16);
    o.w = (unsigned)vs[6] | ((unsigned)vs[7] << 16);
    reinterpret_cast<uint4*>(Wt)[(size_t)c * 2048 + (size_t)n * 4 + u] = o;
  }
}

__global__ __launch_bounds__(512, 2)
void hmlstm_main(const float* __restrict__ hb, const float* __restrict__ hs,
                 const float* __restrict__ ht, const float* __restrict__ cs,
                 const float* __restrict__ zp, const float* __restrict__ zbp,
                 const float* __restrict__ b,
                 const unsigned short* __restrict__ Wt,
                 const float* __restrict__ WLg, float* __restrict__ out)
{
  __shared__ unsigned short ldsW[2][WCH];  // 64 KB double-buffered weights
  __shared__ float ldsA[2][ACH];           // 32 KB double-buffered fp32 A (raw)
  __shared__ float ldsWL[384];             // col-512 weights (sz path)

  const int tid  = threadIdx.x;
  const int l    = tid & 63;
  const int wv   = tid >> 6;   // 0..7
  const int ws   = wv & 3;     // col slice
  const int wr   = wv >> 2;    // row half
  const int q    = l >> 4;     // quad 0..3
  const int lr   = l & 15;
  const int row0 = blockIdx.x * MT;

  if (tid < 384) ldsWL[tid] = WLg[tid];   // coalesced (prep emits contiguous)

  // MFMA row scales (rows wr*64 + s*16 + lr)
  float zrow[4], zbrow[4];
  #pragma unroll
  for (int s = 0; s < 4; ++s) {
    int r = row0 + wr * 64 + s * 16 + lr;
    zrow[s] = zp[r]; zbrow[s] = zbp[r];
  }
  // sz row (rows wv*16 + l/4)
  const int rsz = wv * 16 + (l >> 2);
  const float z_sz  = zp[row0 + rsz];
  const float zb_sz = zbp[row0 + rsz];
  double szacc = 0.0;

  f32x4 acc[4][8];
  {
    f32x4 zf = {0.f, 0.f, 0.f, 0.f};
    #pragma unroll
    for (int i = 0; i < 4; ++i)
      #pragma unroll
      for (int j = 0; j < 8; ++j) acc[i][j] = zf;
  }

  // ---- staging (issue-only, no consumption) ----
  auto stageW = [&](int c, int buf) {
    const unsigned short* gW = Wt + (size_t)c * WCH;
    #pragma unroll
    for (int r = 0; r < 4; ++r) {
      int eo = (wv * 4 + r) * 512;
      async_copy16(gW + eo + l * 8, &ldsW[buf][eo]);
    }
  };
  // A: raw fp32 copy with in-mapping XOR swizzle (LDS dest linear; global addr per-lane)
  auto stageA = [&](int c, int buf) {
    const float* src = (c < 4) ? hb : (c < 8) ? hs : ht;
    const int co = (c & 3) * 32;
    #pragma unroll
    for (int r = 0; r < 2; ++r) {
      int U0 = (wv * 2 + r) * 64;
      int m  = (U0 + l) >> 3;                 // block-local row
      int ul = ((U0 + l) & 7) ^ (m & 7);      // logical 16B unit (swizzled)
      async_copy16(src + (size_t)(row0 + m) * 128 + co + ul * 4,
                   &ldsA[buf][U0 * 4]);
    }
  };

  stageW(0, 0); stageA(0, 0);   // prologue prefetch

  #pragma unroll
  for (int kc = 0; kc < NKC; ++kc) {
    const int cur = kc & 1;
    if (kc < NKC - 1) { stageW(kc + 1, cur ^ 1); stageA(kc + 1, cur ^ 1); }
    __builtin_amdgcn_sched_barrier(0);
    if (kc < NKC - 1) __builtin_amdgcn_s_waitcnt(0x0076);  // vmcnt(6) lgkmcnt(0): keep 6 newest in flight
    else              __builtin_amdgcn_s_waitcnt(0x0070);  // vmcnt(0) lgkmcnt(0)
    __builtin_amdgcn_s_barrier();
    __builtin_amdgcn_sched_barrier(0);

    // ---- compute on buffer cur ----
    short8 bfr[8];
    #pragma unroll
    for (int tn = 0; tn < 8; ++tn) {
      int nc = (tn >> 1) * 128 + ws * 32 + (tn & 1) * 16 + lr;
      bfr[tn] = *(const short8*)&ldsW[cur][nc * BK + ((q ^ ((nc >> 1) & 3)) * 8)];
    }
    const float scm = (kc < 4) ? 0.f : (kc < 8) ? 1.f : 2.f;  // selector
    #pragma unroll
    for (int s = 0; s < 4; ++s) {
      int m = wr * 64 + s * 16 + lr;
      const float sc = (kc < 4) ? zbrow[s] : (kc < 8) ? 1.f : zrow[s];
      f32x4 a0 = *(const f32x4*)&ldsA[cur][m * 32 + (((q * 2)     ^ (m & 7)) * 4)];
      f32x4 a1 = *(const f32x4*)&ldsA[cur][m * 32 + (((q * 2 + 1) ^ (m & 7)) * 4)];
      a0 *= sc; a1 *= sc;
      short8 af;
      ((unsigned*)&af)[0] = pk_bf2(a0.x, a0.y);
      ((unsigned*)&af)[1] = pk_bf2(a0.z, a0.w);
      ((unsigned*)&af)[2] = pk_bf2(a1.x, a1.y);
      ((unsigned*)&af)[3] = pk_bf2(a1.z, a1.w);
      #pragma unroll
      for (int tn = 0; tn < 8; ++tn)
        acc[s][tn] = __builtin_amdgcn_mfma_f32_16x16x32_bf16(af, bfr[tn], acc[s][tn], 0, 0, 0);
    }
    // ---- sz partial: fp64 dot over this chunk's fp32 A tile ----
    {
      int kq = (l & 3) * 2;
      f32x4 s0 = *(const f32x4*)&ldsA[cur][rsz * 32 + ((kq       ^ (rsz & 7)) * 4)];
      f32x4 s1 = *(const f32x4*)&ldsA[cur][rsz * 32 + (((kq + 1) ^ (rsz & 7)) * 4)];
      const float* wl = &ldsWL[kc * 32 + (l & 3) * 8];
      double d = (double)s0.x * wl[0] + (double)s0.y * wl[1]
               + (double)s0.z * wl[2] + (double)s0.w * wl[3]
               + (double)s1.x * wl[4] + (double)s1.y * wl[5]
               + (double)s1.z * wl[6] + (double)s1.w * wl[7];
      const float scz = (kc < 4) ? zb_sz : (kc < 8) ? 1.f : z_sz;
      szacc += (double)scz * d;
      (void)scm;
    }
    __builtin_amdgcn_sched_barrier(0);
    __builtin_amdgcn_s_barrier();   // plain barrier: reads of cur done before next overwrite
  }

  // ---- z_new: reduce 4 k-partials per row (lanes l^1, l^2), threshold ----
  szacc += __shfl_xor(szacc, 1);
  szacc += __shfl_xor(szacc, 2);
  if ((l & 3) == 0) {
    float s = (float)(szacc + (double)b[512]);
    out[ZOFF + row0 + rsz] = (s > 0.f) ? 1.f : 0.f;
  }

  // ---- epilogue: all four gates for (row,col) live in this lane's acc ----
  float bias[2][4];
  #pragma unroll
  for (int th = 0; th < 2; ++th) {
    const int col = ws * 32 + th * 16 + lr;
    bias[th][0] = b[col];       bias[th][1] = b[128 + col];
    bias[th][2] = b[256 + col]; bias[th][3] = b[384 + col];
  }
  #pragma unroll
  for (int s = 0; s < 4; ++s) {
    #pragma unroll
    for (int r = 0; r < 4; ++r) {
      const int row = row0 + wr * 64 + s * 16 + q * 4 + r;  // C/D: row=quad*4+reg
      const float zr  = zp[row];
      const float zbr = zbp[row];
      const size_t rowoff = (size_t)row * 128;
      #pragma unroll
      for (int th = 0; th < 2; ++th) {
        const int col = ws * 32 + th * 16 + lr;             // C/D: col=lane&15
        const size_t off = rowoff + col;
        float si = acc[s][0 + th][r] + bias[th][0];
        float sg = acc[s][2 + th][r] + bias[th][1];
        float so = acc[s][4 + th][r] + bias[th][2];
        float sf = acc[s][6 + th][r] + bias[th][3];
        float iv = sigm(si);
        float gv = tanh_fast(sg);
        float ov = sigm(so);
        float fv = sigm(sf);
        float ig = iv * gv;
        float cv = cs[off];
        float hv = hs[off];
        float cn = (zr == 1.f) ? ig : ((zbr == 0.f) ? cv : cv * fv + ig);
        float hn = (zr == 0.f && zbr == 0.f) ? hv : tanh_fast(cn) * ov;
        out[off]        = hn;
        out[COFF + off] = cn;
      }
    }
  }
}

extern "C" void kernel_launch(void* const* d_in, const int* in_sizes, int n_in,
                              void* d_out, int out_size, void* d_ws, size_t ws_size,
                              hipStream_t stream) {
  const float* hb  = (const float*)d_in[0];
  const float* hs  = (const float*)d_in[1];
  const float* ht  = (const float*)d_in[2];
  const float* cs  = (const float*)d_in[3];
  const float* zp  = (const float*)d_in[4];
  const float* zbp = (const float*)d_in[5];
  const float* W   = (const float*)d_in[6];
  const float* R   = (const float*)d_in[7];
  const float* U   = (const float*)d_in[8];
  const float* b   = (const float*)d_in[9];
  unsigned short* Wt = (unsigned short*)d_ws;          // 393216 B bf16 weights
  float* WL = (float*)(Wt + (size_t)NKC * WCH);        // + 1536 B fp32 col-512
  float* out = (float*)d_out;

  prep_weights<<<dim3(48), dim3(256), 0, stream>>>(W, R, U, Wt, WL);
  hmlstm_main<<<dim3(65536 / MT), dim3(NT), 0, stream>>>(
      hb, hs, ht, cs, zp, zbp, b, Wt, WL, out);
}